// Round 15
// baseline (306.816 us; speedup 1.0000x reference)
//
#include <hip/hip_runtime.h>

typedef unsigned char u8;
typedef unsigned int u32;
typedef long long i64;
typedef __attribute__((ext_vector_type(2))) float f32x2;
typedef __attribute__((ext_vector_type(4))) float f32x4;

#define NROWS 400000
#define DIM 192
#define GRPB 64
#define GNBLK (NROWS / GRPB)    /* 6250 */
#define FRPB 128
#define FNBLK (NROWS / FRPB)    /* 3125 */
#define SLAB 25
#define RBLK (GNBLK / SLAB)     /* 250 */
#define PITCH 200               /* LDS pitch bytes: 50 dwords -> minimal 4/bank on b64 reads */
#define BN_EPS 1e-5f

#if __has_builtin(__builtin_amdgcn_cvt_pk_fp8_f32) && __has_builtin(__builtin_amdgcn_cvt_pk_f32_fp8)
#define HW_FP8 1
#endif

__device__ __forceinline__ u32 enc1_fp8(float f) {  // f32 -> e4m3fn, RNE
  float a = fabsf(f);
  u32 sg = (__float_as_uint(f) >> 24) & 0x80u;
  a = fminf(a, 448.f);
  u32 em;
  if (a >= 0.015625f) {
    u32 b = __float_as_uint(a);
    b += 0x0007FFFFu + ((b >> 20) & 1u);
    em = ((b >> 20) & 0xFFFu) - 960u;
  } else {
    em = (u32)(int)rintf(a * 512.f);
  }
  return sg | em;
}

__device__ __forceinline__ u32 pack4_fp8(float f0, float f1, float f2, float f3) {
#ifdef HW_FP8
  int w = 0;
  w = __builtin_amdgcn_cvt_pk_fp8_f32(f0, f1, w, false);
  w = __builtin_amdgcn_cvt_pk_fp8_f32(f2, f3, w, true);
  return (u32)w;
#else
  return enc1_fp8(f0) | (enc1_fp8(f1) << 8) | (enc1_fp8(f2) << 16) | (enc1_fp8(f3) << 24);
#endif
}

#ifndef HW_FP8
__device__ __forceinline__ float dec1_fp8(u32 b) {
  u32 em = b & 0x7Fu;
  float vn = __uint_as_float((em + 960u) << 20);
  float vd = (float)em * 0.001953125f;
  float v = (em >= 8u) ? vn : vd;
  return (b & 0x80u) ? -v : v;
}
#endif

__device__ __forceinline__ void unpack8_fp8(uint2 p, float (&f)[8]) {
#ifdef HW_FP8
  f32x2 v0 = __builtin_amdgcn_cvt_pk_f32_fp8(p.x, false);
  f32x2 v1 = __builtin_amdgcn_cvt_pk_f32_fp8(p.x, true);
  f32x2 v2 = __builtin_amdgcn_cvt_pk_f32_fp8(p.y, false);
  f32x2 v3 = __builtin_amdgcn_cvt_pk_f32_fp8(p.y, true);
  f[0] = v0[0]; f[1] = v0[1]; f[2] = v1[0]; f[3] = v1[1];
  f[4] = v2[0]; f[5] = v2[1]; f[6] = v3[0]; f[7] = v3[1];
#else
#pragma unroll
  for (int i = 0; i < 4; ++i) f[i] = dec1_fp8((p.x >> (8 * i)) & 0xFFu);
#pragma unroll
  for (int i = 0; i < 4; ++i) f[4 + i] = dec1_fp8((p.y >> (8 * i)) & 0xFFu);
#endif
}

__device__ __forceinline__ i64 u2l(uint2 u) {
  union { uint2 u2; i64 l; } c; c.u2 = u; return c.l;
}

// Weights -> fp8 e4m3, transposed col-major. W3 padded to 16 cols (8 zeros).
// Zeroes the loss accumulator and the two reduction counters every replay.
__global__ void prep_w(const float* __restrict__ W1, const float* __restrict__ W2,
                       const float* __restrict__ W3, u8* __restrict__ W1q,
                       u8* __restrict__ W2q, u8* __restrict__ W3q,
                       float* __restrict__ accum, u32* __restrict__ counters) {
  int idx = blockIdx.x * 256 + threadIdx.x;
  if (idx == 0) { *accum = 0.f; }
  if (idx < 4) counters[idx] = 0u;
  if (idx < DIM * DIM) {
    int h = idx / DIM, d = idx % DIM;
    W1q[idx] = (u8)enc1_fp8(W1[d * DIM + h]);
    W2q[idx] = (u8)enc1_fp8(W2[d * DIM + h]);
  } else if (idx < DIM * DIM + 16 * DIM) {
    int j = idx - DIM * DIM;
    int c = j / DIM, k = j % DIM;
    W3q[j] = (c < 8) ? (u8)enc1_fp8(W3[k * 8 + c]) : (u8)0;
  }
}

// Fused fp8 GEMM + column (sum,sumsq) partials (row-major, coalesced).
// 64-row tiles; PITCH=200 gives minimal 4/bank LDS access on b64 fragment reads.
// Bias dropped: BN(XW+b) == BN(XW).
// LAYER==1: A = X (fp32->fp8). LAYER==2: A = ReLU(BN1(fp8 Y1)); in-place out.
template <int LAYER>
__global__ __launch_bounds__(256, 4) void gemm_bn(
    const float* __restrict__ Xf, const u8* __restrict__ Yin8,
    u8* __restrict__ Yout8, const u8* __restrict__ Wq,
    const float* __restrict__ scale_in, const float* __restrict__ shift_in,
    float* __restrict__ partials) {
  __shared__ __align__(16) char smem[GRPB * PITCH];  // 12.8 KB
  const int t = threadIdx.x;
  const int bid = blockIdx.x;
  const size_t row0 = (size_t)bid * GRPB;

  if (LAYER == 1) {
    const float4* Xv = (const float4*)(Xf + row0 * DIM);
#pragma unroll
    for (int j = 0; j < 12; ++j) {
      int e = j * 256 + t;  // 64 rows x 48 float4 -> u32 of 4 fp8
      int r = e / 48, c4 = e % 48;
      float4 v = Xv[e];
      *(u32*)(smem + r * PITCH + c4 * 4) = pack4_fp8(v.x, v.y, v.z, v.w);
    }
  } else {
    const uint2* Yin2 = (const uint2*)(Yin8 + row0 * DIM);
#pragma unroll
    for (int j = 0; j < 6; ++j) {
      int e = j * 256 + t;  // 64 rows x 24 uint2 (8 fp8)
      int r = e / 24, c8 = e % 24;
      int cb8 = c8 * 8;
      uint2 p = Yin2[r * 24 + c8];
      float f[8];
      unpack8_fp8(p, f);
      float4 sc0 = *(const float4*)&scale_in[cb8];
      float4 sc1 = *(const float4*)&scale_in[cb8 + 4];
      float4 sh0 = *(const float4*)&shift_in[cb8];
      float4 sh1 = *(const float4*)&shift_in[cb8 + 4];
      float scv[8] = {sc0.x, sc0.y, sc0.z, sc0.w, sc1.x, sc1.y, sc1.z, sc1.w};
      float shv[8] = {sh0.x, sh0.y, sh0.z, sh0.w, sh1.x, sh1.y, sh1.z, sh1.w};
      float h[8];
#pragma unroll
      for (int i = 0; i < 8; ++i) h[i] = fmaxf(f[i] * scv[i] + shv[i], 0.f);
      uint2 o;
      o.x = pack4_fp8(h[0], h[1], h[2], h[3]);
      o.y = pack4_fp8(h[4], h[5], h[6], h[7]);
      *(uint2*)(smem + r * PITCH + cb8) = o;
    }
  }
  __syncthreads();

  const int lane = t & 63, wv = t >> 6;
  const int cb = wv * 48;  // wave owns 48 output cols x 64 rows
  const int lr = lane & 15;
  const int g = lane >> 4;  // 0..3
  const int kg = g * 8;

  f32x4 acc[4][3];
#pragma unroll
  for (int rt = 0; rt < 4; ++rt)
#pragma unroll
    for (int ct = 0; ct < 3; ++ct) acc[rt][ct] = (f32x4){0.f, 0.f, 0.f, 0.f};

#pragma unroll
  for (int ks = 0; ks < 6; ++ks) {
    const int k0 = ks * 32 + kg;  // byte offset (1B/elem)
    i64 b0 = u2l(*(const uint2*)(Wq + (size_t)(cb + lr) * DIM + k0));
    i64 b1 = u2l(*(const uint2*)(Wq + (size_t)(cb + 16 + lr) * DIM + k0));
    i64 b2 = u2l(*(const uint2*)(Wq + (size_t)(cb + 32 + lr) * DIM + k0));
#pragma unroll
    for (int rt = 0; rt < 4; ++rt) {
      i64 a = u2l(*(const uint2*)(smem + (rt * 16 + lr) * PITCH + k0));
      acc[rt][0] = __builtin_amdgcn_mfma_f32_16x16x32_fp8_fp8(b0, a, acc[rt][0], 0, 0, 0);
      acc[rt][1] = __builtin_amdgcn_mfma_f32_16x16x32_fp8_fp8(b1, a, acc[rt][1], 0, 0, 0);
      acc[rt][2] = __builtin_amdgcn_mfma_f32_16x16x32_fp8_fp8(b2, a, acc[rt][2], 0, 0, 0);
    }
  }
  __syncthreads();  // fragment reads done; reuse smem as u32 tile [64][50]

  // Epilogue: stats (fp32) + pack fp8 -> LDS
  f32x4 s[3], q[3];
#pragma unroll
  for (int ct = 0; ct < 3; ++ct) { s[ct] = (f32x4){0,0,0,0}; q[ct] = (f32x4){0,0,0,0}; }
  u32* lds32 = (u32*)smem;
#pragma unroll
  for (int rt = 0; rt < 4; ++rt) {
    const int row = rt * 16 + lr;
#pragma unroll
    for (int ct = 0; ct < 3; ++ct) {
      f32x4 v = acc[rt][ct];
      s[ct][0] += v[0]; s[ct][1] += v[1]; s[ct][2] += v[2]; s[ct][3] += v[3];
      q[ct][0] += v[0]*v[0]; q[ct][1] += v[1]*v[1]; q[ct][2] += v[2]*v[2]; q[ct][3] += v[3]*v[3];
      lds32[row * 50 + wv * 12 + ct * 4 + g] = pack4_fp8(v[0], v[1], v[2], v[3]);
    }
  }
  __syncthreads();

  // Coalesced flush: uint2-pair LDS reads (200B pitch is 8B-aligned) -> uint4 stores
  uint4* Yo4 = (uint4*)(Yout8 + row0 * DIM);
#pragma unroll
  for (int u = 0; u < 3; ++u) {
    int idx4 = u * 256 + t;       // uint4 index in [64*12]
    int row = idx4 / 12, m = idx4 % 12;
    uint2 a = *(const uint2*)&lds32[row * 50 + m * 4];
    uint2 b = *(const uint2*)&lds32[row * 50 + m * 4 + 2];
    Yo4[idx4] = (uint4){a.x, a.y, b.x, b.y};
  }

  // Stats: reduce over rows (lane&15), write row-major partials (coalesced)
#pragma unroll
  for (int ct = 0; ct < 3; ++ct)
#pragma unroll
    for (int off = 1; off <= 8; off <<= 1)
#pragma unroll
      for (int i = 0; i < 4; ++i) {
        s[ct][i] += __shfl_xor(s[ct][i], off);
        q[ct][i] += __shfl_xor(q[ct][i], off);
      }
  if (lr == 0) {
    size_t base = (size_t)bid * 384 + cb + g * 4;
#pragma unroll
    for (int ct = 0; ct < 3; ++ct) {
      *(f32x4*)&partials[base + ct * 16] = s[ct];
      *(f32x4*)&partials[base + ct * 16 + 192] = q[ct];
    }
  }
}

// Fused stage-1 + stage-2 reduction: 250 blocks each reduce a contiguous slab
// [SLAB][384] -> out2[b][384]; the LAST completing block (device counter) sums
// out2 over all 250 rows (L2-hot, coalesced) and writes the BN affine params.
__global__ __launch_bounds__(384) void bn_reduce_fin(
    const float* __restrict__ partials, float* __restrict__ out2,
    const float* __restrict__ g, const float* __restrict__ be,
    float* __restrict__ scale, float* __restrict__ shift,
    u32* __restrict__ done) {
  const int b = blockIdx.x, t = threadIdx.x;
  const float* p = partials + (size_t)b * SLAB * 384;
  float v = 0.f;
#pragma unroll
  for (int r = 0; r < SLAB; ++r) v += p[r * 384 + t];
  out2[b * 384 + t] = v;

  // last-block reduction
  __shared__ bool amLast;
  __threadfence();
  __syncthreads();
  if (t == 0) amLast = (atomicAdd(done, 1u) == (u32)(RBLK - 1));
  __syncthreads();
  if (amLast) {
    float tot = 0.f;
    for (int r = 0; r < RBLK; ++r) tot += out2[r * 384 + t];
    __shared__ float tots[384];
    tots[t] = tot;
    __syncthreads();
    if (t < 192) {
      float s = tots[t], q = tots[t + 192];
      float mean = s / (float)NROWS;
      float var = q / (float)NROWS - mean * mean;
      float inv = rsqrtf(var + BN_EPS);
      float sc = g[t] * inv;
      scale[t] = sc;
      shift[t] = be[t] - mean * sc;
    }
  }
}

// LDS staging of Y2 + BN2+ReLU at stage time, fp8 MFMA Linear[192x16pad]
// + sigmoid + log_softmax + NLL. Last completing block writes mean loss to out.
__global__ __launch_bounds__(256, 4) void final_loss(
    const u8* __restrict__ Y2, const int* __restrict__ labels,
    const float* __restrict__ scale2, const float* __restrict__ shift2,
    const u8* __restrict__ W3q, const float* __restrict__ b3,
    float* __restrict__ accum, u32* __restrict__ counter,
    float* __restrict__ out) {
  __shared__ __align__(16) char smem[FRPB * PITCH];  // 25.6 KB
  __shared__ __align__(16) float sc2[DIM], sh2[DIM];
  __shared__ float red[4];
  const int t = threadIdx.x;
  const size_t row0 = (size_t)blockIdx.x * FRPB;

  if (t < 48) ((float4*)sc2)[t] = ((const float4*)scale2)[t];
  else if (t < 96) ((float4*)sh2)[t - 48] = ((const float4*)shift2)[t - 48];
  __syncthreads();

  const uint4* Yp4 = (const uint4*)(Y2 + row0 * DIM);
#pragma unroll
  for (int j = 0; j < 6; ++j) {
    int idx4 = j * 256 + t;
    int row = idx4 / 12, c0 = (idx4 % 12) * 16;
    uint4 p = Yp4[idx4];
    uint2 plo = {p.x, p.y}, phi = {p.z, p.w};
    float fa[8], fb[8];
    unpack8_fp8(plo, fa);
    unpack8_fp8(phi, fb);
    float h[16];
#pragma unroll
    for (int i = 0; i < 8; ++i) {
      h[i] = fmaxf(fa[i] * sc2[c0 + i] + sh2[c0 + i], 0.f);
      h[8 + i] = fmaxf(fb[i] * sc2[c0 + 8 + i] + sh2[c0 + 8 + i], 0.f);
    }
    uint2 o0 = {pack4_fp8(h[0], h[1], h[2], h[3]), pack4_fp8(h[4], h[5], h[6], h[7])};
    uint2 o1 = {pack4_fp8(h[8], h[9], h[10], h[11]), pack4_fp8(h[12], h[13], h[14], h[15])};
    *(uint2*)(smem + row * PITCH + c0) = o0;
    *(uint2*)(smem + row * PITCH + c0 + 8) = o1;
  }
  __syncthreads();

  const int lane = t & 63, wv = t >> 6;
  const int lr = lane & 15, g = lane >> 4, kg = g * 8;
  i64 wf[6];
#pragma unroll
  for (int ks = 0; ks < 6; ++ks)
    wf[ks] = u2l(*(const uint2*)(W3q + lr * DIM + ks * 32 + kg));
  const float b3v = (lr < 8) ? b3[lr] : 0.f;

  float contrib = 0.f;
#pragma unroll
  for (int tl = 0; tl < 2; ++tl) {
    const int rbase = wv * 32 + tl * 16;
    f32x4 acc = (f32x4){0.f, 0.f, 0.f, 0.f};
#pragma unroll
    for (int ks = 0; ks < 6; ++ks) {
      const int k0 = ks * 32 + kg;
      i64 a = u2l(*(const uint2*)(smem + (rbase + lr) * PITCH + k0));
      acc = __builtin_amdgcn_mfma_f32_16x16x32_fp8_fp8(a, wf[ks], acc, 0, 0, 0);
    }
    // lane: rows rbase+g*4+i, class col = lr (0-7 valid, 8-15 zero-pad)
#pragma unroll
    for (int i = 0; i < 4; ++i) {
      float pv = 1.f / (1.f + __expf(-(acc[i] + b3v)));
      float m = pv;
      m = fmaxf(m, __shfl_xor(m, 1));
      m = fmaxf(m, __shfl_xor(m, 2));
      m = fmaxf(m, __shfl_xor(m, 4));
      float e = __expf(pv - m);
      e += __shfl_xor(e, 1);
      e += __shfl_xor(e, 2);
      e += __shfl_xor(e, 4);
      int lab = labels[row0 + rbase + g * 4 + i];
      if (lr == lab) contrib += m + __logf(e) - pv;
    }
  }
#pragma unroll
  for (int off = 1; off < 64; off <<= 1) contrib += __shfl_xor(contrib, off);
  if (lane == 0) red[wv] = contrib;
  __syncthreads();
  if (t == 0) {
    atomicAdd(accum, red[0] + red[1] + red[2] + red[3]);
    __threadfence();
    u32 prev = atomicAdd(counter, 1u);
    if (prev == (u32)(FNBLK - 1)) {
      float a = *(volatile float*)accum;
      out[0] = a / (float)NROWS;
    }
  }
}

extern "C" void kernel_launch(void* const* d_in, const int* in_sizes, int n_in,
                              void* d_out, int out_size, void* d_ws, size_t ws_size,
                              hipStream_t stream) {
  const float* inputs = (const float*)d_in[0];
  const int* labels   = (const int*)d_in[1];
  const float* W1  = (const float*)d_in[2];
  const float* g1  = (const float*)d_in[4];
  const float* be1 = (const float*)d_in[5];
  const float* W2  = (const float*)d_in[6];
  const float* g2  = (const float*)d_in[8];
  const float* be2 = (const float*)d_in[9];
  const float* W3  = (const float*)d_in[10];
  const float* b3  = (const float*)d_in[11];
  float* out = (float*)d_out;

  char* ws = (char*)d_ws;
  u8* W1q       = (u8*)(ws + 0);         // 36864
  u8* W2q       = (u8*)(ws + 40960);     // 36864
  u8* W3q       = (u8*)(ws + 81920);     // 3072
  float* scale1 = (float*)(ws + 98304);
  float* shift1 = (float*)(ws + 99072);
  float* scale2 = (float*)(ws + 99840);
  float* shift2 = (float*)(ws + 100608);
  float* accum  = (float*)(ws + 101376);
  u32* counters = (u32*)(ws + 101440);     // [0]=bn1 done, [1]=bn2 done, [2]=loss done
  float* out2   = (float*)(ws + 102400);   // 250*384*4 = 384000
  float* partials = (float*)(ws + 524288); // 6250*384*4 = 9.6 MB
  u8* Ybuf      = (u8*)(ws + 16777216);    // 400000*192 = 76.8 MB (fp8)

  prep_w<<<156, 256, 0, stream>>>(W1, W2, W3, W1q, W2q, W3q, accum, counters);
  gemm_bn<1><<<GNBLK, 256, 0, stream>>>(inputs, nullptr, Ybuf, W1q, nullptr, nullptr, partials);
  bn_reduce_fin<<<RBLK, 384, 0, stream>>>(partials, out2, g1, be1, scale1, shift1, &counters[0]);
  gemm_bn<2><<<GNBLK, 256, 0, stream>>>(nullptr, Ybuf, Ybuf, W2q, scale1, shift1, partials);
  bn_reduce_fin<<<RBLK, 384, 0, stream>>>(partials, out2, g2, be2, scale2, shift2, &counters[1]);
  final_loss<<<FNBLK, 256, 0, stream>>>(Ybuf, labels, scale2, shift2, W3q, b3, accum, &counters[2], out);
}

// Round 17
// 223.620 us; speedup vs baseline: 1.3720x; 1.3720x over previous
//
#include <hip/hip_runtime.h>

typedef unsigned char u8;
typedef unsigned int u32;
typedef long long i64;
typedef __attribute__((ext_vector_type(2))) float f32x2;
typedef __attribute__((ext_vector_type(4))) float f32x4;

#define NROWS 400000
#define DIM 192
#define GRPB 64
#define GNBLK (NROWS / GRPB)    /* 6250 */
#define FRPB 128
#define FNBLK (NROWS / FRPB)    /* 3125 */
#define SLAB 25
#define RBLK (GNBLK / SLAB)     /* 250 */
#define PITCH 200               /* LDS pitch bytes: 50 dwords -> minimal 4/bank on b64 reads */
#define BN_EPS 1e-5f

#if __has_builtin(__builtin_amdgcn_cvt_pk_fp8_f32) && __has_builtin(__builtin_amdgcn_cvt_pk_f32_fp8)
#define HW_FP8 1
#endif

__device__ __forceinline__ u32 enc1_fp8(float f) {  // f32 -> e4m3fn, RNE
  float a = fabsf(f);
  u32 sg = (__float_as_uint(f) >> 24) & 0x80u;
  a = fminf(a, 448.f);
  u32 em;
  if (a >= 0.015625f) {
    u32 b = __float_as_uint(a);
    b += 0x0007FFFFu + ((b >> 20) & 1u);
    em = ((b >> 20) & 0xFFFu) - 960u;
  } else {
    em = (u32)(int)rintf(a * 512.f);
  }
  return sg | em;
}

__device__ __forceinline__ u32 pack4_fp8(float f0, float f1, float f2, float f3) {
#ifdef HW_FP8
  int w = 0;
  w = __builtin_amdgcn_cvt_pk_fp8_f32(f0, f1, w, false);
  w = __builtin_amdgcn_cvt_pk_fp8_f32(f2, f3, w, true);
  return (u32)w;
#else
  return enc1_fp8(f0) | (enc1_fp8(f1) << 8) | (enc1_fp8(f2) << 16) | (enc1_fp8(f3) << 24);
#endif
}

#ifndef HW_FP8
__device__ __forceinline__ float dec1_fp8(u32 b) {
  u32 em = b & 0x7Fu;
  float vn = __uint_as_float((em + 960u) << 20);
  float vd = (float)em * 0.001953125f;
  float v = (em >= 8u) ? vn : vd;
  return (b & 0x80u) ? -v : v;
}
#endif

__device__ __forceinline__ void unpack8_fp8(uint2 p, float (&f)[8]) {
#ifdef HW_FP8
  f32x2 v0 = __builtin_amdgcn_cvt_pk_f32_fp8(p.x, false);
  f32x2 v1 = __builtin_amdgcn_cvt_pk_f32_fp8(p.x, true);
  f32x2 v2 = __builtin_amdgcn_cvt_pk_f32_fp8(p.y, false);
  f32x2 v3 = __builtin_amdgcn_cvt_pk_f32_fp8(p.y, true);
  f[0] = v0[0]; f[1] = v0[1]; f[2] = v1[0]; f[3] = v1[1];
  f[4] = v2[0]; f[5] = v2[1]; f[6] = v3[0]; f[7] = v3[1];
#else
#pragma unroll
  for (int i = 0; i < 4; ++i) f[i] = dec1_fp8((p.x >> (8 * i)) & 0xFFu);
#pragma unroll
  for (int i = 0; i < 4; ++i) f[4 + i] = dec1_fp8((p.y >> (8 * i)) & 0xFFu);
#endif
}

__device__ __forceinline__ i64 u2l(uint2 u) {
  union { uint2 u2; i64 l; } c; c.u2 = u; return c.l;
}

// Weights -> fp8 e4m3, transposed col-major. W3 padded to 16 cols (8 zeros).
__global__ void prep_w(const float* __restrict__ W1, const float* __restrict__ W2,
                       const float* __restrict__ W3, u8* __restrict__ W1q,
                       u8* __restrict__ W2q, u8* __restrict__ W3q) {
  int idx = blockIdx.x * 256 + threadIdx.x;
  if (idx < DIM * DIM) {
    int h = idx / DIM, d = idx % DIM;
    W1q[idx] = (u8)enc1_fp8(W1[d * DIM + h]);
    W2q[idx] = (u8)enc1_fp8(W2[d * DIM + h]);
  } else if (idx < DIM * DIM + 16 * DIM) {
    int j = idx - DIM * DIM;
    int c = j / DIM, k = j % DIM;
    W3q[j] = (c < 8) ? (u8)enc1_fp8(W3[k * 8 + c]) : (u8)0;
  }
}

// Fused fp8 GEMM + column (sum,sumsq) partials (row-major, coalesced).
// 64-row tiles; PITCH=200 gives minimal 4/bank LDS access on b64 fragment reads.
// LAYER1's X read is NON-TEMPORAL (307 MB single-use stream) so the concurrent
// Y1 writes stay resident in Infinity Cache for gemm2's re-read.
// Bias dropped: BN(XW+b) == BN(XW).
// LAYER==1: A = X (fp32->fp8). LAYER==2: A = ReLU(BN1(fp8 Y1)); in-place out.
template <int LAYER>
__global__ __launch_bounds__(256, 4) void gemm_bn(
    const float* __restrict__ Xf, const u8* __restrict__ Yin8,
    u8* __restrict__ Yout8, const u8* __restrict__ Wq,
    const float* __restrict__ scale_in, const float* __restrict__ shift_in,
    float* __restrict__ partials) {
  __shared__ __align__(16) char smem[GRPB * PITCH];  // 12.8 KB
  const int t = threadIdx.x;
  const int bid = blockIdx.x;
  const size_t row0 = (size_t)bid * GRPB;

  if (LAYER == 1) {
    const f32x4* Xv = (const f32x4*)(Xf + row0 * DIM);
#pragma unroll
    for (int j = 0; j < 12; ++j) {
      int e = j * 256 + t;  // 64 rows x 48 float4 -> u32 of 4 fp8
      int r = e / 48, c4 = e % 48;
      f32x4 v = __builtin_nontemporal_load(&Xv[e]);
      *(u32*)(smem + r * PITCH + c4 * 4) = pack4_fp8(v[0], v[1], v[2], v[3]);
    }
  } else {
    const uint2* Yin2 = (const uint2*)(Yin8 + row0 * DIM);
#pragma unroll
    for (int j = 0; j < 6; ++j) {
      int e = j * 256 + t;  // 64 rows x 24 uint2 (8 fp8)
      int r = e / 24, c8 = e % 24;
      int cb8 = c8 * 8;
      uint2 p = Yin2[r * 24 + c8];
      float f[8];
      unpack8_fp8(p, f);
      float4 sc0 = *(const float4*)&scale_in[cb8];
      float4 sc1 = *(const float4*)&scale_in[cb8 + 4];
      float4 sh0 = *(const float4*)&shift_in[cb8];
      float4 sh1 = *(const float4*)&shift_in[cb8 + 4];
      float scv[8] = {sc0.x, sc0.y, sc0.z, sc0.w, sc1.x, sc1.y, sc1.z, sc1.w};
      float shv[8] = {sh0.x, sh0.y, sh0.z, sh0.w, sh1.x, sh1.y, sh1.z, sh1.w};
      float h[8];
#pragma unroll
      for (int i = 0; i < 8; ++i) h[i] = fmaxf(f[i] * scv[i] + shv[i], 0.f);
      uint2 o;
      o.x = pack4_fp8(h[0], h[1], h[2], h[3]);
      o.y = pack4_fp8(h[4], h[5], h[6], h[7]);
      *(uint2*)(smem + r * PITCH + cb8) = o;
    }
  }
  __syncthreads();

  const int lane = t & 63, wv = t >> 6;
  const int cb = wv * 48;  // wave owns 48 output cols x 64 rows
  const int lr = lane & 15;
  const int g = lane >> 4;  // 0..3
  const int kg = g * 8;

  f32x4 acc[4][3];
#pragma unroll
  for (int rt = 0; rt < 4; ++rt)
#pragma unroll
    for (int ct = 0; ct < 3; ++ct) acc[rt][ct] = (f32x4){0.f, 0.f, 0.f, 0.f};

#pragma unroll
  for (int ks = 0; ks < 6; ++ks) {
    const int k0 = ks * 32 + kg;  // byte offset (1B/elem)
    i64 b0 = u2l(*(const uint2*)(Wq + (size_t)(cb + lr) * DIM + k0));
    i64 b1 = u2l(*(const uint2*)(Wq + (size_t)(cb + 16 + lr) * DIM + k0));
    i64 b2 = u2l(*(const uint2*)(Wq + (size_t)(cb + 32 + lr) * DIM + k0));
#pragma unroll
    for (int rt = 0; rt < 4; ++rt) {
      i64 a = u2l(*(const uint2*)(smem + (rt * 16 + lr) * PITCH + k0));
      acc[rt][0] = __builtin_amdgcn_mfma_f32_16x16x32_fp8_fp8(b0, a, acc[rt][0], 0, 0, 0);
      acc[rt][1] = __builtin_amdgcn_mfma_f32_16x16x32_fp8_fp8(b1, a, acc[rt][1], 0, 0, 0);
      acc[rt][2] = __builtin_amdgcn_mfma_f32_16x16x32_fp8_fp8(b2, a, acc[rt][2], 0, 0, 0);
    }
  }
  __syncthreads();  // fragment reads done; reuse smem as u32 tile [64][50]

  // Epilogue: stats (fp32) + pack fp8 -> LDS
  f32x4 s[3], q[3];
#pragma unroll
  for (int ct = 0; ct < 3; ++ct) { s[ct] = (f32x4){0,0,0,0}; q[ct] = (f32x4){0,0,0,0}; }
  u32* lds32 = (u32*)smem;
#pragma unroll
  for (int rt = 0; rt < 4; ++rt) {
    const int row = rt * 16 + lr;
#pragma unroll
    for (int ct = 0; ct < 3; ++ct) {
      f32x4 v = acc[rt][ct];
      s[ct][0] += v[0]; s[ct][1] += v[1]; s[ct][2] += v[2]; s[ct][3] += v[3];
      q[ct][0] += v[0]*v[0]; q[ct][1] += v[1]*v[1]; q[ct][2] += v[2]*v[2]; q[ct][3] += v[3]*v[3];
      lds32[row * 50 + wv * 12 + ct * 4 + g] = pack4_fp8(v[0], v[1], v[2], v[3]);
    }
  }
  __syncthreads();

  // Coalesced flush: uint2-pair LDS reads (200B pitch is 8B-aligned) -> uint4 stores
  uint4* Yo4 = (uint4*)(Yout8 + row0 * DIM);
#pragma unroll
  for (int u = 0; u < 3; ++u) {
    int idx4 = u * 256 + t;       // uint4 index in [64*12]
    int row = idx4 / 12, m = idx4 % 12;
    uint2 a = *(const uint2*)&lds32[row * 50 + m * 4];
    uint2 b = *(const uint2*)&lds32[row * 50 + m * 4 + 2];
    Yo4[idx4] = (uint4){a.x, a.y, b.x, b.y};
  }

  // Stats: reduce over rows (lane&15), write row-major partials (coalesced)
#pragma unroll
  for (int ct = 0; ct < 3; ++ct)
#pragma unroll
    for (int off = 1; off <= 8; off <<= 1)
#pragma unroll
      for (int i = 0; i < 4; ++i) {
        s[ct][i] += __shfl_xor(s[ct][i], off);
        q[ct][i] += __shfl_xor(q[ct][i], off);
      }
  if (lr == 0) {
    size_t base = (size_t)bid * 384 + cb + g * 4;
#pragma unroll
    for (int ct = 0; ct < 3; ++ct) {
      *(f32x4*)&partials[base + ct * 16] = s[ct];
      *(f32x4*)&partials[base + ct * 16 + 192] = q[ct];
    }
  }
}

// Stage 1: coalesced slab reduction of partials [GNBLK][384] -> out2 [RBLK][384]
__global__ __launch_bounds__(384) void bn_reduce1(const float* __restrict__ partials,
                                                  float* __restrict__ out2) {
  const int b = blockIdx.x, t = threadIdx.x;
  const float* p = partials + (size_t)b * SLAB * 384;
  float v = 0.f;
#pragma unroll
  for (int r = 0; r < SLAB; ++r) v += p[r * 384 + t];
  out2[b * 384 + t] = v;
}

// Stage 2: final reduce + BN affine params; also zeroes the loss accumulator.
__global__ __launch_bounds__(384) void bn_fin2(
    const float* __restrict__ out2, const float* __restrict__ g,
    const float* __restrict__ be, float* __restrict__ scale,
    float* __restrict__ shift, float* accum) {
  __shared__ float tot[384];
  const int t = threadIdx.x;
  float v = 0.f;
  for (int b = 0; b < RBLK; ++b) v += out2[b * 384 + t];
  tot[t] = v;
  __syncthreads();
  if (t < 192) {
    float s = tot[t], q = tot[t + 192];
    float mean = s / (float)NROWS;
    float var = q / (float)NROWS - mean * mean;
    float inv = rsqrtf(var + BN_EPS);
    float sc = g[t] * inv;
    scale[t] = sc;
    shift[t] = be[t] - mean * sc;
  }
  if (t == 0) *accum = 0.f;
}

// LDS staging of Y2 + BN2+ReLU at stage time, fp8 MFMA Linear[192x16pad]
// + sigmoid + log_softmax + NLL accumulate. PITCH=200 (minimal bank aliasing).
__global__ __launch_bounds__(256, 4) void final_loss(
    const u8* __restrict__ Y2, const int* __restrict__ labels,
    const float* __restrict__ scale2, const float* __restrict__ shift2,
    const u8* __restrict__ W3q, const float* __restrict__ b3, float* accum) {
  __shared__ __align__(16) char smem[FRPB * PITCH];  // 25.6 KB
  __shared__ __align__(16) float sc2[DIM], sh2[DIM];
  __shared__ float red[4];
  const int t = threadIdx.x;
  const size_t row0 = (size_t)blockIdx.x * FRPB;

  if (t < 48) ((float4*)sc2)[t] = ((const float4*)scale2)[t];
  else if (t < 96) ((float4*)sh2)[t - 48] = ((const float4*)shift2)[t - 48];
  __syncthreads();

  const uint4* Yp4 = (const uint4*)(Y2 + row0 * DIM);
#pragma unroll
  for (int j = 0; j < 6; ++j) {
    int idx4 = j * 256 + t;
    int row = idx4 / 12, c0 = (idx4 % 12) * 16;
    uint4 p = Yp4[idx4];
    uint2 plo = {p.x, p.y}, phi = {p.z, p.w};
    float fa[8], fb[8];
    unpack8_fp8(plo, fa);
    unpack8_fp8(phi, fb);
    float h[16];
#pragma unroll
    for (int i = 0; i < 8; ++i) {
      h[i] = fmaxf(fa[i] * sc2[c0 + i] + sh2[c0 + i], 0.f);
      h[8 + i] = fmaxf(fb[i] * sc2[c0 + 8 + i] + sh2[c0 + 8 + i], 0.f);
    }
    uint2 o0 = {pack4_fp8(h[0], h[1], h[2], h[3]), pack4_fp8(h[4], h[5], h[6], h[7])};
    uint2 o1 = {pack4_fp8(h[8], h[9], h[10], h[11]), pack4_fp8(h[12], h[13], h[14], h[15])};
    *(uint2*)(smem + row * PITCH + c0) = o0;
    *(uint2*)(smem + row * PITCH + c0 + 8) = o1;
  }
  __syncthreads();

  const int lane = t & 63, wv = t >> 6;
  const int lr = lane & 15, g = lane >> 4, kg = g * 8;
  i64 wf[6];
#pragma unroll
  for (int ks = 0; ks < 6; ++ks)
    wf[ks] = u2l(*(const uint2*)(W3q + lr * DIM + ks * 32 + kg));
  const float b3v = (lr < 8) ? b3[lr] : 0.f;

  float contrib = 0.f;
#pragma unroll
  for (int tl = 0; tl < 2; ++tl) {
    const int rbase = wv * 32 + tl * 16;
    f32x4 acc = (f32x4){0.f, 0.f, 0.f, 0.f};
#pragma unroll
    for (int ks = 0; ks < 6; ++ks) {
      const int k0 = ks * 32 + kg;
      i64 a = u2l(*(const uint2*)(smem + (rbase + lr) * PITCH + k0));
      acc = __builtin_amdgcn_mfma_f32_16x16x32_fp8_fp8(a, wf[ks], acc, 0, 0, 0);
    }
    // lane: rows rbase+g*4+i, class col = lr (0-7 valid, 8-15 zero-pad)
#pragma unroll
    for (int i = 0; i < 4; ++i) {
      float pv = 1.f / (1.f + __expf(-(acc[i] + b3v)));
      float m = pv;
      m = fmaxf(m, __shfl_xor(m, 1));
      m = fmaxf(m, __shfl_xor(m, 2));
      m = fmaxf(m, __shfl_xor(m, 4));
      float e = __expf(pv - m);
      e += __shfl_xor(e, 1);
      e += __shfl_xor(e, 2);
      e += __shfl_xor(e, 4);
      int lab = labels[row0 + rbase + g * 4 + i];
      if (lr == lab) contrib += m + __logf(e) - pv;
    }
  }
#pragma unroll
  for (int off = 1; off < 64; off <<= 1) contrib += __shfl_xor(contrib, off);
  if (lane == 0) red[wv] = contrib;
  __syncthreads();
  if (t == 0) atomicAdd(accum, red[0] + red[1] + red[2] + red[3]);
}

__global__ void finalize(const float* __restrict__ accum, float* __restrict__ out) {
  if (threadIdx.x == 0) out[0] = accum[0] / (float)NROWS;
}

extern "C" void kernel_launch(void* const* d_in, const int* in_sizes, int n_in,
                              void* d_out, int out_size, void* d_ws, size_t ws_size,
                              hipStream_t stream) {
  const float* inputs = (const float*)d_in[0];
  const int* labels   = (const int*)d_in[1];
  const float* W1  = (const float*)d_in[2];
  const float* g1  = (const float*)d_in[4];
  const float* be1 = (const float*)d_in[5];
  const float* W2  = (const float*)d_in[6];
  const float* g2  = (const float*)d_in[8];
  const float* be2 = (const float*)d_in[9];
  const float* W3  = (const float*)d_in[10];
  const float* b3  = (const float*)d_in[11];
  float* out = (float*)d_out;

  char* ws = (char*)d_ws;
  u8* W1q       = (u8*)(ws + 0);         // 36864
  u8* W2q       = (u8*)(ws + 40960);     // 36864
  u8* W3q       = (u8*)(ws + 81920);     // 3072
  float* scale1 = (float*)(ws + 98304);
  float* shift1 = (float*)(ws + 99072);
  float* scale2 = (float*)(ws + 99840);
  float* shift2 = (float*)(ws + 100608);
  float* accum  = (float*)(ws + 101376);
  float* out2   = (float*)(ws + 102400);   // 250*384*4 = 384000
  float* partials = (float*)(ws + 524288); // 6250*384*4 = 9.6 MB
  u8* Ybuf      = (u8*)(ws + 16777216);    // 400000*192 = 76.8 MB (fp8)

  prep_w<<<156, 256, 0, stream>>>(W1, W2, W3, W1q, W2q, W3q);
  gemm_bn<1><<<GNBLK, 256, 0, stream>>>(inputs, nullptr, Ybuf, W1q, nullptr, nullptr, partials);
  bn_reduce1<<<RBLK, 384, 0, stream>>>(partials, out2);
  bn_fin2<<<1, 384, 0, stream>>>(out2, g1, be1, scale1, shift1, accum);
  gemm_bn<2><<<GNBLK, 256, 0, stream>>>(nullptr, Ybuf, Ybuf, W2q, scale1, shift1, partials);
  bn_reduce1<<<RBLK, 384, 0, stream>>>(partials, out2);
  bn_fin2<<<1, 384, 0, stream>>>(out2, g2, be2, scale2, shift2, accum);
  final_loss<<<FNBLK, 256, 0, stream>>>(Ybuf, labels, scale2, shift2, W3q, b3, accum);
  finalize<<<1, 64, 0, stream>>>(accum, out);
}